// Round 12
// baseline (104.291 us; speedup 1.0000x reference)
//
#include <hip/hip_runtime.h>

// Problem constants
#define HW    16384   // 128*128
#define WIDTH 128
#define LOG2E    1.4426950408889634f
#define RS_LOG2E 0.5101464200926166f   // (1/sqrt(8)) * LOG2E

// ws layout (dwords):
//  [0, 3072):     wfb   — bf16 [96 j][64 k] fused feature B-matrix (logit rows pre-scaled by LOG2E)
//  [3072, 3168):  biasV — f32 [96] bias for valid pixels (logit part incl. RS_LOG2E)
//  [3168, 3264):  biasP — f32 [96] bias for padded pixels
//  [3264, 4288):  wot   — fp16 [32 col][64 k] Wo^T
//  [4288, 4576):  rel   — f32 [32][9], pre-scaled by LOG2E
#define WFB_DWORDS 3072
#define BIASV_OFF  3072
#define BIASP_OFF  3168
#define WOT_OFF    3264
#define REL_OFF    4288
#define WS_DWORDS  4576

typedef short bshort8 __attribute__((ext_vector_type(8)));
typedef _Float16 half8 __attribute__((ext_vector_type(8)));
typedef float f32x4   __attribute__((ext_vector_type(4)));
typedef unsigned u32x4 __attribute__((ext_vector_type(4)));
typedef unsigned u32x2 __attribute__((ext_vector_type(2)));

static __device__ inline unsigned short f2bf(float f) {
    unsigned u = __builtin_bit_cast(unsigned, f);
    unsigned r = u + 0x7fff + ((u >> 16) & 1);   // RNE
    return (unsigned short)(r >> 16);
}
static __device__ inline unsigned cvtpk(float lo, float hi) {  // 2xf32 -> packed bf16
    unsigned d;
    asm("v_cvt_pk_bf16_f32 %0, %1, %2" : "=v"(d) : "v"(lo), "v"(hi));
    return d;
}
static __device__ inline unsigned pkrtz(float lo, float hi) {  // 2xf32 -> packed fp16
    return __builtin_bit_cast(unsigned, __builtin_amdgcn_cvt_pkrtz(lo, hi));
}
static __device__ inline float lo16f(unsigned u) {
    return (float)__builtin_bit_cast(_Float16, (unsigned short)(u & 0xffffu));
}
static __device__ inline float hi16f(unsigned u) {
    return (float)__builtin_bit_cast(_Float16, (unsigned short)(u >> 16));
}
// o += bcast(a.lo/hi) * v   (fp16 pairs)
static __device__ inline unsigned pkfma16_lo(unsigned o, unsigned a, unsigned v) {
    asm("v_pk_fma_f16 %0, %1, %2, %0 op_sel:[0,0,0] op_sel_hi:[0,1,1]"
        : "+v"(o) : "v"(a), "v"(v));
    return o;
}
static __device__ inline unsigned pkfma16_hi(unsigned o, unsigned a, unsigned v) {
    asm("v_pk_fma_f16 %0, %1, %2, %0 op_sel:[1,0,0] op_sel_hi:[1,1,1]"
        : "+v"(o) : "v"(a), "v"(v));
    return o;
}
// d = a * bcast(r.lo/hi)
static __device__ inline unsigned pkmul16_lo(unsigned a, unsigned r) {
    unsigned d;
    asm("v_pk_mul_f16 %0, %1, %2 op_sel:[0,0] op_sel_hi:[0,1]"
        : "=v"(d) : "v"(r), "v"(a));
    return d;
}
static __device__ inline unsigned pkmul16_hi(unsigned a, unsigned r) {
    unsigned d;
    asm("v_pk_mul_f16 %0, %1, %2 op_sel:[1,0] op_sel_hi:[1,1]"
        : "=v"(d) : "v"(r), "v"(a));
    return d;
}

// ---------------------------------------------------------------------------
// K0: fold weights — 8 blocks, each owns 12 feature rows of wfb (bf16),
//     + f32 bias tables (biasV/biasP).
// ---------------------------------------------------------------------------
__global__ __launch_bounds__(256) void k0_fuse(
    const float* __restrict__ up_query,
    const float* __restrict__ Wk, const float* __restrict__ bk,
    const float* __restrict__ Wv, const float* __restrict__ bv,
    const float* __restrict__ Wq, const float* __restrict__ bq,
    const float* __restrict__ Wka, const float* __restrict__ bka,
    const float* __restrict__ Wva, const float* __restrict__ bva,
    const float* __restrict__ Wo, const float* __restrict__ rel_pos,
    float* __restrict__ ws)
{
    __shared__ float qcS[4][64];
    __shared__ float WkT[64][65];   // [e][c] transposed
    __shared__ float WvT[64][65];
    __shared__ float colS[12][64];  // per-j K-column (tq*RS_LOG2E or Wva col)
    __shared__ float bred[12][8];
    __shared__ float pred[12][8];

    const int tid = threadIdx.x;
    const int bj  = blockIdx.x;     // 0..7
    const int j0  = bj * 12;

    // qc[q][f] = up_query@Wq + bq  (256 jobs)
    {
        int q = tid >> 6, f = tid & 63;
        float a = bq[f];
        for (int c = 0; c < 64; ++c) a = fmaf(up_query[q*64+c], Wq[c*64+f], a);
        qcS[q][f] = a;
    }
    // stage transposed Wk / Wv
    for (int i = tid; i < 4096; i += 256) {
        int c = i >> 6, e = i & 63;
        WkT[e][c] = Wk[i];
        WvT[e][c] = Wv[i];
    }
    __syncthreads();

    // colS: 768 jobs (12 j x 64 e)
    for (int i = tid; i < 768; i += 256) {
        int jl = i >> 6, e = i & 63;
        int j = j0 + jl;
        float v;
        if (j < 32) {
            int h = j >> 2, qq = j & 3;
            float s = 0.f;
            #pragma unroll
            for (int d = 0; d < 8; ++d)
                s = fmaf(Wka[e*64 + h*8 + d], qcS[qq][h*8 + d], s);
            v = s * RS_LOG2E;
        } else {
            v = Wva[e*64 + (j - 32)];
        }
        colS[jl][e] = v;
    }
    // bias partials: 96 jobs (12 j x 8 d)
    if (tid < 96) {
        int jl = tid >> 3, d = tid & 7;
        int j = j0 + jl;
        if (j < 32) {
            int h = j >> 2, qq = j & 3;
            int fi = h*8 + d;
            float bW = 0.f;
            for (int e = 0; e < 64; ++e) bW = fmaf(bk[e], Wka[e*64 + fi], bW);
            float qv = qcS[qq][fi];
            bred[jl][d] = (2.f*bW + bka[fi]) * qv;   // valid-position part
            pred[jl][d] = bW * qv;                   // valid - pad difference
        } else {
            float s = 0.f;
            for (int e = d*8; e < d*8 + 8; ++e)
                s = fmaf(bv[e], Wva[e*64 + (j - 32)], s);
            bred[jl][d] = s;
            pred[jl][d] = 0.f;
        }
    }
    __syncthreads();

    unsigned* wsd = (unsigned*)ws;
    // weights: 384 jobs (32 c-pairs x 12 j)
    for (int i = tid; i < 384; i += 256) {
        int cp = i & 31, jl = i >> 5;
        int j = j0 + jl;
        const float (*MT)[65] = (j < 32) ? WkT : WvT;
        float o0 = 0.f, o1 = 0.f;
        for (int e = 0; e < 64; ++e) {
            float cv = colS[jl][e];
            o0 = fmaf(MT[e][2*cp],     cv, o0);
            o1 = fmaf(MT[e][2*cp + 1], cv, o1);
        }
        wsd[j*32 + cp] = (unsigned)f2bf(o0) | ((unsigned)f2bf(o1) << 16);
    }
    // biases: 12 jobs
    if (tid < 12) {
        int j = j0 + tid;
        float sv = 0.f, sp = 0.f;
        #pragma unroll
        for (int d = 0; d < 8; ++d) { sv += bred[tid][d]; sp += pred[tid][d]; }
        float bV, bP;
        if (j < 32) { bV = sv * RS_LOG2E; bP = (sv - sp) * RS_LOG2E; }
        else        { bV = sv + bva[j-32]; bP = bva[j-32]; }
        ws[BIASV_OFF + j] = bV;
        ws[BIASP_OFF + j] = bP;
    }
    // wot (fp16) + rel (f32): block 7
    if (bj == 7) {
        for (int i = tid; i < 1024; i += 256) {
            int col = i >> 5, kp = i & 31;
            wsd[WOT_OFF + i] = pkrtz(Wo[(2*kp)*32 + col], Wo[(2*kp + 1)*32 + col]);
        }
        for (int i = tid; i < 288; i += 256)
            ws[REL_OFF + i] = rel_pos[i] * LOG2E;
    }
}

// ---------------------------------------------------------------------------
// K2: LDS shrunk 32768 -> 20000 B (7-8 blocks/CU vs 5):
//  A: x-halo bf16, kq-major [8 chunk][112 px][16B], float2 pair loads (14336B)
//  B: K=64 MFMA feature GEMM (12 MFMA, 4 ds_read) — no flag channels
//  C: f32 bias add (valid ? biasV : biasP, per-pixel select) then fp16 scatter
//     Lh[100][36u16] @0; Vb[100][128B] XOR-swizzled @7200 (ends 20000)
//  D: unchanged numerics (f32 exp2 softmax, fp16 pk-fma PV)
//  E: TWO row-passes over a [128][128B] swizzled buffer (16KB):
//     half lanes write O -> barrier -> 8 MFMA/wave + f32 C -> barrier ->
//     half threads LN+store -> barrier.
// ---------------------------------------------------------------------------
__global__ __launch_bounds__(256, 7) void k2_attn(
    const float* __restrict__ x, const float* __restrict__ ws,
    const float* __restrict__ bo,
    const float* __restrict__ ln_g, const float* __restrict__ ln_b,
    float* __restrict__ out)
{
    __shared__ __align__(16) char smem[20000];
    // A/B : bf16 xA chunk-major: addr = kq*1792 + p*16, kq=0..7      [0,14336)
    // C/D : fp16 Lh[100][36] @0 (7200B); Vb[100][128B] swz @7200     [0,20000)
    // E   : fp16 O[128][128B swz] then f32 C in place                [0,16384)

    const int tid = threadIdx.x;

    // XCD-aware swizzle: 2048 blocks, 8 XCDs -> each XCD one batch image
    const int flat = blockIdx.x;
    const int wg   = (flat & 7) * 256 + (flat >> 3);
    const int tx = wg & 15;
    const int ty = (wg >> 4) & 15;
    const int b  = wg >> 8;

    // ---- Phase A: 400 jobs = 8 chunks x 50 pixel-pairs ----
    #pragma unroll
    for (int it = 0; it < 2; ++it) {
        int i = tid + it*256;
        if (i < 400) {
            int kq = (int)(((unsigned)i * 5243u) >> 18);   // i/50
            int pp = i - kq*50;
            int p0 = pp*2;
            int py = p0/10; int px0 = p0 - py*10;     // px0 even: pair in one row
            int gy = ty*8 - 1 + py, gx0 = tx*8 - 1 + px0;
            bool vy = (unsigned)gy < 128u;
            bool v0 = vy && ((unsigned)gx0 < 128u);
            bool v1 = vy && ((unsigned)(gx0+1) < 128u);
            u32x4 pk0 = {0u,0u,0u,0u}, pk1 = {0u,0u,0u,0u};
            const float* xp = x + ((size_t)b*64 + kq*8)*HW + gy*WIDTH + gx0;
            if (v0 && v1) {
                #pragma unroll
                for (int e = 0; e < 4; ++e) {
                    float2 c0 = *(const float2*)(xp + (size_t)(2*e)*HW);
                    float2 c1 = *(const float2*)(xp + (size_t)(2*e+1)*HW);
                    pk0[e] = cvtpk(c0.x, c1.x);
                    pk1[e] = cvtpk(c0.y, c1.y);
                }
            } else if (v0 || v1) {
                #pragma unroll
                for (int e = 0; e < 4; ++e) {
                    float a0 = 0.f, b0 = 0.f, a1 = 0.f, b1 = 0.f;
                    if (v0) { a0 = xp[(size_t)(2*e)*HW];     b0 = xp[(size_t)(2*e+1)*HW]; }
                    if (v1) { a1 = xp[(size_t)(2*e)*HW + 1]; b1 = xp[(size_t)(2*e+1)*HW + 1]; }
                    pk0[e] = cvtpk(a0, b0);
                    pk1[e] = cvtpk(a1, b1);
                }
            }
            char* dst = smem + kq*1792 + p0*16;
            *(u32x4*)(dst)      = pk0;
            *(u32x4*)(dst + 16) = pk1;
        }
    }
    __syncthreads();

    const int lane = tid & 63;
    const int wv   = tid >> 6;
    const int frow = lane & 15;
    const int kseg = lane >> 4;

    // ---- Phase B: K=64 bf16 feature GEMM ----
    const unsigned short* wfs = (const unsigned short*)ws;
    f32x4 accs[12];
    #pragma unroll
    for (int mi = 0; mi < 2; ++mi) {
        const int mt = wv*2 + mi;
        if (mt < 7) {
            const int prow = mt*16 + frow;
            bshort8 xa0 = *(const bshort8*)(smem + (0*4 + kseg)*1792 + prow*16);
            bshort8 xa1 = *(const bshort8*)(smem + (1*4 + kseg)*1792 + prow*16);
            #pragma unroll
            for (int nt = 0; nt < 6; ++nt) {
                const unsigned short* wrow = wfs + (nt*16 + frow)*64 + kseg*8;
                f32x4 acc = {0.f, 0.f, 0.f, 0.f};
                acc = __builtin_amdgcn_mfma_f32_16x16x32_bf16(*(const bshort8*)(wrow),      xa0, acc, 0, 0, 0);
                acc = __builtin_amdgcn_mfma_f32_16x16x32_bf16(*(const bshort8*)(wrow + 32), xa1, acc, 0, 0, 0);
                accs[mi*6 + nt] = acc;
            }
        }
    }
    __syncthreads();   // xA dead

    // ---- Phase C: f32 bias add + fp16 scatter ----
    unsigned short* Lh = (unsigned short*)smem;            // [100][36]
    char*           Vb = smem + 7200;                      // [100][128B] swz
    const float* biasV = ws + BIASV_OFF;
    const float* biasP = ws + BIASP_OFF;
    #pragma unroll
    for (int mi = 0; mi < 2; ++mi) {
        const int mt = wv*2 + mi;
        if (mt < 7) {
            const int p = mt*16 + frow;
            if (p < 100) {
                int py = p/10, px = p - py*10;
                int gy = ty*8 - 1 + py, gx = tx*8 - 1 + px;
                bool vld = ((unsigned)gy < 128u) && ((unsigned)gx < 128u);
                const float* bb = vld ? biasV : biasP;
                const unsigned vsw = ((unsigned)(p & 7)) << 4;
                #pragma unroll
                for (int nt = 0; nt < 6; ++nt) {
                    f32x4 acc = accs[mi*6 + nt];
                    const f32x4 b4 = *(const f32x4*)(bb + nt*16 + kseg*4);
                    acc[0] += b4[0]; acc[1] += b4[1];
                    acc[2] += b4[2]; acc[3] += b4[3];
                    u32x2 dd = { pkrtz(acc[0], acc[1]), pkrtz(acc[2], acc[3]) };
                    if (nt < 2) {
                        *(u32x2*)(Lh + p*36 + nt*16 + kseg*4) = dd;
                    } else {
                        unsigned off = ((unsigned)((nt-2)*32 + kseg*8)) ^ vsw;
                        *(u32x2*)(Vb + p*128 + off) = dd;
                    }
                }
            }
        }
    }
    __syncthreads();

    // ---- Phase D: wave = head-pair, lane = pixel, all 4 q ----
    const int dpy = lane >> 3, dpx = lane & 7;
    const int pbase = dpy*10 + dpx;
    const float* relw = ws + REL_OFF;

    unsigned od[32];   // packed fp16 O rows: [(q*2+hh)*4 + j]
    #pragma unroll
    for (int hh = 0; hh < 2; ++hh) {
        const int h = wv*2 + hh;
        unsigned apk[2][9];
        float s0 = 0.f, s1 = 0.f, s2 = 0.f, s3 = 0.f;
        const float* rp = relw + h*36;   // rel[h*4+q][n] = rp[q*9 + n]
        const unsigned short* lbase = Lh + pbase*36 + h*4;   // + off*36 elems
        #pragma unroll
        for (int n = 0; n < 9; ++n) {
            const int off = (n/3)*10 + (n%3);
            const u32x2 L4 = *(const u32x2*)(lbase + off*36);
            float e0 = exp2f(lo16f(L4[0]) + rp[n]);
            float e1 = exp2f(hi16f(L4[0]) + rp[9 + n]);
            float e2 = exp2f(lo16f(L4[1]) + rp[18 + n]);
            float e3 = exp2f(hi16f(L4[1]) + rp[27 + n]);
            s0 += e0; s1 += e1; s2 += e2; s3 += e3;
            apk[0][n] = pkrtz(e0, e1);
            apk[1][n] = pkrtz(e2, e3);
        }
        const unsigned r01 = pkrtz(__builtin_amdgcn_rcpf(s0), __builtin_amdgcn_rcpf(s1));
        const unsigned r23 = pkrtz(__builtin_amdgcn_rcpf(s2), __builtin_amdgcn_rcpf(s3));

        unsigned o16[4][4] = {{0u,0u,0u,0u},{0u,0u,0u,0u},{0u,0u,0u,0u},{0u,0u,0u,0u}};
        #pragma unroll
        for (int n = 0; n < 9; ++n) {
            const int pp = pbase + (n/3)*10 + (n%3);
            const u32x4 v4 = *(const u32x4*)(Vb + pp*128
                                 + (((unsigned)(h*16)) ^ (((unsigned)(pp & 7)) << 4)));
            #pragma unroll
            for (int j = 0; j < 4; ++j) {
                o16[0][j] = pkfma16_lo(o16[0][j], apk[0][n], v4[j]);
                o16[1][j] = pkfma16_hi(o16[1][j], apk[0][n], v4[j]);
                o16[2][j] = pkfma16_lo(o16[2][j], apk[1][n], v4[j]);
                o16[3][j] = pkfma16_hi(o16[3][j], apk[1][n], v4[j]);
            }
        }
        #pragma unroll
        for (int j = 0; j < 4; ++j) {
            od[(0*2 + hh)*4 + j] = pkmul16_lo(o16[0][j], r01);
            od[(1*2 + hh)*4 + j] = pkmul16_hi(o16[1][j], r01);
            od[(2*2 + hh)*4 + j] = pkmul16_lo(o16[2][j], r23);
            od[(3*2 + hh)*4 + j] = pkmul16_hi(o16[3][j], r23);
        }
    }
    __syncthreads();   // Lh/Vb dead; E buffer region free

    // ---- Phase E: two row-passes over [128][128B] swizzled buffer ----
    const unsigned short* wotu = (const unsigned short*)ws + WOT_OFF*2;
    half8 bvv[2][2];
    #pragma unroll
    for (int nt = 0; nt < 2; ++nt)
        #pragma unroll
        for (int ks = 0; ks < 2; ++ks)
            bvv[nt][ks] = __builtin_bit_cast(half8,
                *(const u32x4*)(wotu + (nt*16 + frow)*64 + kseg*8 + ks*32));

    const unsigned swO = ((unsigned)(lane & 7)) << 4;
    #pragma unroll
    for (int pass = 0; pass < 2; ++pass) {
        // O-write: lanes [32*pass, 32*pass+32) own buffer rows (lane&31)*4+q
        if ((lane >> 5) == pass) {
            const int l31 = lane & 31;
            #pragma unroll
            for (int q = 0; q < 4; ++q) {
                const int row = l31*4 + q;
                #pragma unroll
                for (int hh = 0; hh < 2; ++hh) {
                    u32x4 w4 = { od[(q*2+hh)*4+0], od[(q*2+hh)*4+1],
                                 od[(q*2+hh)*4+2], od[(q*2+hh)*4+3] };
                    *(u32x4*)(smem + row*128 + (((unsigned)(wv*32 + hh*16)) ^ swO)) = w4;
                }
            }
        }
        __syncthreads();

        // MFMA: wave wv owns buffer rows [wv*32, wv*32+32)
        f32x4 cacc[2][2];
        #pragma unroll
        for (int mtl = 0; mtl < 2; ++mtl)
            #pragma unroll
            for (int nt = 0; nt < 2; ++nt)
                cacc[mtl][nt] = (f32x4){0.f, 0.f, 0.f, 0.f};
        #pragma unroll
        for (int mtl = 0; mtl < 2; ++mtl) {
            const int rowa = wv*32 + mtl*16 + frow;
            const unsigned swa = (((unsigned)(rowa >> 2)) & 7u) << 4;
            #pragma unroll
            for (int ks = 0; ks < 2; ++ks) {
                half8 av = __builtin_bit_cast(half8,
                    *(const u32x4*)(smem + rowa*128 + (((unsigned)(kseg*16 + ks*64)) ^ swa)));
                cacc[mtl][0] = __builtin_amdgcn_mfma_f32_16x16x32_f16(av, bvv[0][ks], cacc[mtl][0], 0, 0, 0);
                cacc[mtl][1] = __builtin_amdgcn_mfma_f32_16x16x32_f16(av, bvv[1][ks], cacc[mtl][1], 0, 0, 0);
            }
        }
        // C-write f32 (same rows)
        #pragma unroll
        for (int mtl = 0; mtl < 2; ++mtl)
            #pragma unroll
            for (int nt = 0; nt < 2; ++nt)
                #pragma unroll
                for (int r = 0; r < 4; ++r) {
                    const int row = wv*32 + mtl*16 + kseg*4 + r;
                    const int col = nt*16 + frow;
                    *(float*)(smem + row*128
                        + (((unsigned)(col*4)) ^ ((((unsigned)(row >> 2)) & 7u) << 4)))
                        = cacc[mtl][nt][r];
                }
        __syncthreads();

        // LN + store: threads with tid in [128*pass, 128*pass+128)
        if ((tid >> 7) == pass) {
            const int brow = tid & 127;
            float cv[32];
            const unsigned sw = (((unsigned)(brow >> 2)) & 7u) << 4;
            #pragma unroll
            for (int j = 0; j < 8; ++j) {
                const f32x4 c4 = *(const f32x4*)(smem + brow*128 + (((unsigned)(j*16)) ^ sw));
                cv[j*4+0] = c4[0]; cv[j*4+1] = c4[1]; cv[j*4+2] = c4[2]; cv[j*4+3] = c4[3];
            }
            float mu = 0.f;
            #pragma unroll
            for (int oc = 0; oc < 32; ++oc) { cv[oc] += bo[oc]; mu += cv[oc]; }
            mu *= (1.f/32.f);
            float var = 0.f;
            #pragma unroll
            for (int oc = 0; oc < 32; ++oc) { float d = cv[oc] - mu; var += d*d; }
            var *= (1.f/32.f);
            const float rstd = rsqrtf(var + 1e-5f);

            const int q   = tid & 3;
            const int pix = tid >> 2;            // global pixel 0..63
            const int gy = ty*8 + (pix >> 3), gx = tx*8 + (pix & 7);
            const int Y = gy*2 + (q >> 1), X = gx*2 + (q & 1);
            float* op = out + (((size_t)b*32)*256 + Y)*256 + X;
            #pragma unroll
            for (int oc = 0; oc < 32; ++oc) {
                float v = (cv[oc] - mu) * rstd * ln_g[oc] + ln_b[oc];
                op[(size_t)oc * 65536] = v;
            }
        }
        __syncthreads();
    }
}

// ---------------------------------------------------------------------------
extern "C" void kernel_launch(void* const* d_in, const int* in_sizes, int n_in,
                              void* d_out, int out_size, void* d_ws, size_t ws_size,
                              hipStream_t stream)
{
    const float* x        = (const float*)d_in[0];
    const float* up_query = (const float*)d_in[1];
    const float* Wk  = (const float*)d_in[2];
    const float* bk  = (const float*)d_in[3];
    const float* Wv  = (const float*)d_in[4];
    const float* bv  = (const float*)d_in[5];
    const float* Wq  = (const float*)d_in[6];
    const float* bq  = (const float*)d_in[7];
    const float* Wka = (const float*)d_in[8];
    const float* bka = (const float*)d_in[9];
    const float* Wva = (const float*)d_in[10];
    const float* bva = (const float*)d_in[11];
    const float* Wo  = (const float*)d_in[12];
    const float* bo  = (const float*)d_in[13];
    const float* rel_pos = (const float*)d_in[14];
    const float* ln_g = (const float*)d_in[15];
    const float* ln_b = (const float*)d_in[16];

    float* ws  = (float*)d_ws;
    float* out = (float*)d_out;

    if (ws_size < (size_t)WS_DWORDS * 4) return;

    k0_fuse<<<8, 256, 0, stream>>>(up_query, Wk, bk, Wv, bv, Wq, bq,
                                   Wka, bka, Wva, bva, Wo, rel_pos, ws);
    k2_attn<<<2048, 256, 0, stream>>>(x, ws, bo, ln_g, ln_b, out);
}

// Round 14
// 61.627 us; speedup vs baseline: 1.6923x; 1.6923x over previous
//
#include <hip/hip_runtime.h>

// Problem constants
#define HW    16384   // 128*128
#define WIDTH 128
#define LOG2E    1.4426950408889634f
#define RS_LOG2E 0.5101464200926166f   // (1/sqrt(8)) * LOG2E

// ws layout (dwords):
//  [0, 4992):     wfb — bf16 [96][104] fused feature B-matrix (logit rows pre-scaled by LOG2E)
//  [4992, 6016):  wot — fp16 [32 col][64 k] Wo^T for the epilogue MFMA
//  [6016, 6304):  rel — f32 [32][9], pre-scaled by LOG2E
#define WFB_DWORDS 4992
#define WOT_OFF    4992
#define REL_OFF    6016
#define WS_DWORDS  6304

typedef short bshort8 __attribute__((ext_vector_type(8)));
typedef _Float16 half8 __attribute__((ext_vector_type(8)));
typedef float f32x4   __attribute__((ext_vector_type(4)));
typedef unsigned u32x4 __attribute__((ext_vector_type(4)));
typedef unsigned u32x2 __attribute__((ext_vector_type(2)));

static __device__ inline unsigned short f2bf(float f) {
    unsigned u = __builtin_bit_cast(unsigned, f);
    unsigned r = u + 0x7fff + ((u >> 16) & 1);   // RNE
    return (unsigned short)(r >> 16);
}
static __device__ inline unsigned cvtpk(float lo, float hi) {  // 2xf32 -> packed bf16
    unsigned d;
    asm("v_cvt_pk_bf16_f32 %0, %1, %2" : "=v"(d) : "v"(lo), "v"(hi));
    return d;
}
static __device__ inline unsigned pkrtz(float lo, float hi) {  // 2xf32 -> packed fp16
    return __builtin_bit_cast(unsigned, __builtin_amdgcn_cvt_pkrtz(lo, hi));
}
static __device__ inline float lo16f(unsigned u) {
    return (float)__builtin_bit_cast(_Float16, (unsigned short)(u & 0xffffu));
}
static __device__ inline float hi16f(unsigned u) {
    return (float)__builtin_bit_cast(_Float16, (unsigned short)(u >> 16));
}
// o += bcast(a.lo/hi) * v   (fp16 pairs)
static __device__ inline unsigned pkfma16_lo(unsigned o, unsigned a, unsigned v) {
    asm("v_pk_fma_f16 %0, %1, %2, %0 op_sel:[0,0,0] op_sel_hi:[0,1,1]"
        : "+v"(o) : "v"(a), "v"(v));
    return o;
}
static __device__ inline unsigned pkfma16_hi(unsigned o, unsigned a, unsigned v) {
    asm("v_pk_fma_f16 %0, %1, %2, %0 op_sel:[1,0,0] op_sel_hi:[1,1,1]"
        : "+v"(o) : "v"(a), "v"(v));
    return o;
}
// d = a * bcast(r.lo/hi)
static __device__ inline unsigned pkmul16_lo(unsigned a, unsigned r) {
    unsigned d;
    asm("v_pk_mul_f16 %0, %1, %2 op_sel:[0,0] op_sel_hi:[0,1]"
        : "=v"(d) : "v"(r), "v"(a));
    return d;
}
static __device__ inline unsigned pkmul16_hi(unsigned a, unsigned r) {
    unsigned d;
    asm("v_pk_mul_f16 %0, %1, %2 op_sel:[1,0] op_sel_hi:[1,1]"
        : "=v"(d) : "v"(r), "v"(a));
    return d;
}

// ---------------------------------------------------------------------------
// K0: fold weights — 8 blocks, each owns 12 feature rows of wfb.
// ---------------------------------------------------------------------------
__global__ __launch_bounds__(256) void k0_fuse(
    const float* __restrict__ up_query,
    const float* __restrict__ Wk, const float* __restrict__ bk,
    const float* __restrict__ Wv, const float* __restrict__ bv,
    const float* __restrict__ Wq, const float* __restrict__ bq,
    const float* __restrict__ Wka, const float* __restrict__ bka,
    const float* __restrict__ Wva, const float* __restrict__ bva,
    const float* __restrict__ Wo, const float* __restrict__ rel_pos,
    float* __restrict__ ws)
{
    __shared__ float qcS[4][64];
    __shared__ float WkT[64][65];   // [e][c] transposed
    __shared__ float WvT[64][65];
    __shared__ float colS[12][64];  // per-j K-column (tq*RS_LOG2E or Wva col)
    __shared__ float bred[12][8];
    __shared__ float pred[12][8];

    const int tid = threadIdx.x;
    const int bj  = blockIdx.x;     // 0..7
    const int j0  = bj * 12;

    // qc[q][f] = up_query@Wq + bq  (256 jobs)
    {
        int q = tid >> 6, f = tid & 63;
        float a = bq[f];
        for (int c = 0; c < 64; ++c) a = fmaf(up_query[q*64+c], Wq[c*64+f], a);
        qcS[q][f] = a;
    }
    // stage transposed Wk / Wv
    for (int i = tid; i < 4096; i += 256) {
        int c = i >> 6, e = i & 63;
        WkT[e][c] = Wk[i];
        WvT[e][c] = Wv[i];
    }
    __syncthreads();

    // colS: 768 jobs (12 j x 64 e)
    for (int i = tid; i < 768; i += 256) {
        int jl = i >> 6, e = i & 63;
        int j = j0 + jl;
        float v;
        if (j < 32) {
            int h = j >> 2, qq = j & 3;
            float s = 0.f;
            #pragma unroll
            for (int d = 0; d < 8; ++d)
                s = fmaf(Wka[e*64 + h*8 + d], qcS[qq][h*8 + d], s);
            v = s * RS_LOG2E;
        } else {
            v = Wva[e*64 + (j - 32)];
        }
        colS[jl][e] = v;
    }
    // bias partials: 96 jobs (12 j x 8 d)
    if (tid < 96) {
        int jl = tid >> 3, d = tid & 7;
        int j = j0 + jl;
        if (j < 32) {
            int h = j >> 2, qq = j & 3;
            int fi = h*8 + d;
            float bW = 0.f;
            for (int e = 0; e < 64; ++e) bW = fmaf(bk[e], Wka[e*64 + fi], bW);
            float qv = qcS[qq][fi];
            bred[jl][d] = (2.f*bW + bka[fi]) * qv;   // valid-position part
            pred[jl][d] = bW * qv;                   // valid - pad difference
        } else {
            float s = 0.f;
            for (int e = d*8; e < d*8 + 8; ++e)
                s = fmaf(bv[e], Wva[e*64 + (j - 32)], s);
            bred[jl][d] = s;
            pred[jl][d] = 0.f;
        }
    }
    __syncthreads();

    unsigned* wsd = (unsigned*)ws;
    // main GEMM + emit: 384 jobs (32 c-pairs x 12 j)
    for (int i = tid; i < 384; i += 256) {
        int cp = i & 31, jl = i >> 5;
        int j = j0 + jl;
        const float (*MT)[65] = (j < 32) ? WkT : WvT;
        float o0 = 0.f, o1 = 0.f;
        for (int e = 0; e < 64; ++e) {
            float cv = colS[jl][e];
            o0 = fmaf(MT[e][2*cp],     cv, o0);
            o1 = fmaf(MT[e][2*cp + 1], cv, o1);
        }
        wsd[j*52 + cp] = (unsigned)f2bf(o0) | ((unsigned)f2bf(o1) << 16);
    }
    // bias dword (kd=32) + zero cols (kd 33..51): 12 x 20 jobs
    for (int i = tid; i < 240; i += 256) {
        int jl = i / 20, kd = 32 + (i % 20);
        int j = j0 + jl;
        unsigned val = 0u;
        if (kd == 32) {
            float sv = 0.f, sp = 0.f;
            #pragma unroll
            for (int d = 0; d < 8; ++d) { sv += bred[jl][d]; sp += pred[jl][d]; }
            float bf_, pd_;
            if (j < 32) { bf_ = sv * RS_LOG2E; pd_ = (sv - sp) * RS_LOG2E; }
            else        { bf_ = sv + bva[j-32]; pd_ = bva[j-32]; }
            val = (unsigned)f2bf(bf_) | ((unsigned)f2bf(pd_) << 16);
        }
        wsd[j*52 + kd] = val;
    }
    // wot (fp16) + rel: block 7
    if (bj == 7) {
        for (int i = tid; i < 1024; i += 256) {
            int col = i >> 5, kp = i & 31;
            wsd[WOT_OFF + i] = pkrtz(Wo[(2*kp)*32 + col], Wo[(2*kp + 1)*32 + col]);
        }
        for (int i = tid; i < 288; i += 256)
            ws[REL_OFF + i] = rel_pos[i] * LOG2E;
    }
}

// ---------------------------------------------------------------------------
// K2: fused pipeline, LDS = 32768 -> 5 blocks/CU.  (round-8 measured-best)
//  A: stage 10x10 x-halo bf16 (p<100, ch<96 region) into xA rows (XOR-swz)
//  B: MFMA bf16 feature GEMM; wave owns 2 consecutive mt -> xa fragments
//     loaded ONCE and reused across the 6 nt tiles (33 -> 6 ds_read_b128)
//  C: scatter fp16 -> Lh[100][36]u16, Vh[100][72]u16
//  D: wave = head-pair, lane = pixel: logits read as b64 (4 q at once),
//     no-max exp2 softmax, PV fp16 pk-fma with op_sel broadcast
//  E: O fp16 [256][128B swz] -> mfma f16 x WoT -> C f32 -> LN -> store
// ---------------------------------------------------------------------------
__global__ __launch_bounds__(256, 5) void k2_attn(
    const float* __restrict__ x, const float* __restrict__ ws,
    const float* __restrict__ bo,
    const float* __restrict__ ln_g, const float* __restrict__ ln_b,
    float* __restrict__ out)
{
    __shared__ __align__(16) char smem[32768];
    // A/B : bf16 xA rows p=0..111, 256B stride, byte ^= (p&7)<<4     [0,28672)
    // C/D : fp16 Lh[100][36] @0 (7200B); fp16 Vh[100][72] @8192 (14400B)
    // E   : fp16 O[256][128B swz] then f32 C in place                [0,32768)

    const int tid = threadIdx.x;

    // XCD-aware swizzle: 2048 blocks, 8 XCDs -> each XCD gets one batch image
    const int flat = blockIdx.x;
    const int wg   = (flat & 7) * 256 + (flat >> 3);
    const int tx = wg & 15;
    const int ty = (wg >> 4) & 15;
    const int b  = wg >> 8;

    // ---- Phase A: 1200 jobs = 12 chunks x 100 pixels (i = kq*100 + p) ----
    #pragma unroll
    for (int it = 0; it < 5; ++it) {
        int i = tid + it*256;
        if (i < 1200) {
            int kq = (int)(((unsigned)i * 5243u) >> 19);   // i/100
            int p  = i - kq*100;
            int py = p / 10, px = p - py*10;
            int gy = ty*8 - 1 + py, gx = tx*8 - 1 + px;
            bool valid = ((unsigned)gy < 128u) && ((unsigned)gx < 128u);
            u32x4 pack = {0u, 0u, 0u, 0u};
            if (kq < 8) {
                if (valid) {
                    const float* xp = x + ((size_t)b*64 + kq*8)*HW + gy*WIDTH + gx;
                    #pragma unroll
                    for (int e = 0; e < 4; ++e)
                        pack[e] = cvtpk(xp[(size_t)(2*e)*HW], xp[(size_t)(2*e+1)*HW]);
                }
            } else if (kq == 8) {
                pack[0] = valid ? 0x00003f80u : 0x3f800000u;  // bf16 flags ch64/65
            }
            // kq 9..11 stay zero (ch 72..95 must be 0: wfb zeros x NaN-garbage hazard)
            *(u32x4*)(smem + p*256 + (((unsigned)(kq*16)) ^ (((unsigned)(p & 7)) << 4))) = pack;
        }
    }
    __syncthreads();

    const int lane = tid & 63;
    const int wv   = tid >> 6;
    const int frow = lane & 15;
    const int kseg = lane >> 4;

    // ---- Phase B: bf16 feature GEMM, xa reuse across nt ----
    const unsigned short* wfs = (const unsigned short*)ws;
    f32x4 accs[12];
    #pragma unroll
    for (int mi = 0; mi < 2; ++mi) {
        const int mt = wv*2 + mi;
        if (mt < 7) {
            const int prow = mt*16 + frow;
            const unsigned psw = ((unsigned)(prow & 7)) << 4;
            bshort8 xa0 = *(const bshort8*)(smem + prow*256 + (((unsigned)(kseg*16))       ^ psw));
            bshort8 xa1 = *(const bshort8*)(smem + prow*256 + (((unsigned)(kseg*16 + 64))  ^ psw));
            bshort8 xa2 = *(const bshort8*)(smem + prow*256 + (((unsigned)(kseg*16 + 128)) ^ psw));
            #pragma unroll
            for (int nt = 0; nt < 6; ++nt) {
                const unsigned short* wrow = wfs + (nt*16 + frow)*104 + kseg*8;
                f32x4 acc = {0.f, 0.f, 0.f, 0.f};
                acc = __builtin_amdgcn_mfma_f32_16x16x32_bf16(*(const bshort8*)(wrow),      xa0, acc, 0, 0, 0);
                acc = __builtin_amdgcn_mfma_f32_16x16x32_bf16(*(const bshort8*)(wrow + 32), xa1, acc, 0, 0, 0);
                acc = __builtin_amdgcn_mfma_f32_16x16x32_bf16(*(const bshort8*)(wrow + 64), xa2, acc, 0, 0, 0);
                accs[mi*6 + nt] = acc;
            }
        }
    }
    __syncthreads();   // xA dead

    // ---- Phase C: fp16 scatter ----
    unsigned short* Lh = (unsigned short*)smem;            // [100][36]
    unsigned short* Vh = (unsigned short*)(smem + 8192);   // [100][72]
    #pragma unroll
    for (int mi = 0; mi < 2; ++mi) {
        const int mt = wv*2 + mi;
        if (mt < 7) {
            const int p = mt*16 + frow;
            if (p < 100) {
                #pragma unroll
                for (int nt = 0; nt < 6; ++nt) {
                    const f32x4 acc = accs[mi*6 + nt];
                    u32x2 dd = { pkrtz(acc[0], acc[1]), pkrtz(acc[2], acc[3]) };
                    if (nt < 2) *(u32x2*)(Lh + p*36 + nt*16 + kseg*4) = dd;
                    else        *(u32x2*)(Vh + p*72 + (nt-2)*16 + kseg*4) = dd;
                }
            }
        }
    }
    __syncthreads();

    // ---- Phase D: wave = head-pair, lane = pixel, all 4 q ----
    const int dpy = lane >> 3, dpx = lane & 7;
    const int pbase = dpy*10 + dpx;
    const float* relw = ws + REL_OFF;

    unsigned od[32];   // packed fp16 O rows: [(q*2+hh)*4 + j]
    #pragma unroll
    for (int hh = 0; hh < 2; ++hh) {
        const int h = wv*2 + hh;
        unsigned apk[2][9];
        float s0 = 0.f, s1 = 0.f, s2 = 0.f, s3 = 0.f;
        const float* rp = relw + h*36;   // rel[h*4+q][n] = rp[q*9 + n]
        #pragma unroll
        for (int n = 0; n < 9; ++n) {
            const int off = (n/3)*10 + (n%3);
            const u32x2 L4 = *(const u32x2*)(Lh + (pbase + off)*36 + h*4);
            float e0 = exp2f(lo16f(L4[0]) + rp[n]);
            float e1 = exp2f(hi16f(L4[0]) + rp[9 + n]);
            float e2 = exp2f(lo16f(L4[1]) + rp[18 + n]);
            float e3 = exp2f(hi16f(L4[1]) + rp[27 + n]);
            s0 += e0; s1 += e1; s2 += e2; s3 += e3;
            apk[0][n] = pkrtz(e0, e1);
            apk[1][n] = pkrtz(e2, e3);
        }
        const unsigned r01 = pkrtz(__builtin_amdgcn_rcpf(s0), __builtin_amdgcn_rcpf(s1));
        const unsigned r23 = pkrtz(__builtin_amdgcn_rcpf(s2), __builtin_amdgcn_rcpf(s3));

        unsigned o16[4][4] = {{0u,0u,0u,0u},{0u,0u,0u,0u},{0u,0u,0u,0u},{0u,0u,0u,0u}};
        #pragma unroll
        for (int n = 0; n < 9; ++n) {
            const int off = (n/3)*10 + (n%3);
            const u32x4 v4 = *(const u32x4*)(Vh + (pbase + off)*72 + h*8);
            #pragma unroll
            for (int j = 0; j < 4; ++j) {
                o16[0][j] = pkfma16_lo(o16[0][j], apk[0][n], v4[j]);
                o16[1][j] = pkfma16_hi(o16[1][j], apk[0][n], v4[j]);
                o16[2][j] = pkfma16_lo(o16[2][j], apk[1][n], v4[j]);
                o16[3][j] = pkfma16_hi(o16[3][j], apk[1][n], v4[j]);
            }
        }
        #pragma unroll
        for (int j = 0; j < 4; ++j) {
            od[(0*2 + hh)*4 + j] = pkmul16_lo(o16[0][j], r01);
            od[(1*2 + hh)*4 + j] = pkmul16_hi(o16[1][j], r01);
            od[(2*2 + hh)*4 + j] = pkmul16_lo(o16[2][j], r23);
            od[(3*2 + hh)*4 + j] = pkmul16_hi(o16[3][j], r23);
        }
    }
    __syncthreads();   // Lh/Vh dead

    // O-writes: row = lane*4+q (128B rows, byte ^= ((row>>2)&7)<<4 = (lane&7)<<4)
    {
        const unsigned sw = ((unsigned)(lane & 7)) << 4;
        #pragma unroll
        for (int q = 0; q < 4; ++q) {
            const int row = lane*4 + q;
            #pragma unroll
            for (int hh = 0; hh < 2; ++hh) {
                u32x4 w4 = { od[(q*2+hh)*4+0], od[(q*2+hh)*4+1],
                             od[(q*2+hh)*4+2], od[(q*2+hh)*4+3] };
                *(u32x4*)(smem + row*128 + (((unsigned)(wv*32 + hh*16)) ^ sw)) = w4;
            }
        }
    }
    __syncthreads();   // O complete (cross-wave)

    // ---- Phase E: Wo via fp16 MFMA; wave wv owns rows [wv*64, wv*64+64) ----
    const unsigned short* wotu = (const unsigned short*)ws + WOT_OFF*2;
    half8 av[4][2];
    #pragma unroll
    for (int mt = 0; mt < 4; ++mt) {
        const int row = wv*64 + mt*16 + frow;
        const unsigned sw = (((unsigned)(row >> 2)) & 7u) << 4;
        #pragma unroll
        for (int ks = 0; ks < 2; ++ks)
            av[mt][ks] = __builtin_bit_cast(half8,
                *(const u32x4*)(smem + row*128 + (((unsigned)(kseg*16 + ks*64)) ^ sw)));
    }
    half8 bv_[2][2];
    #pragma unroll
    for (int nt = 0; nt < 2; ++nt) {
        const int col = nt*16 + frow;
        #pragma unroll
        for (int ks = 0; ks < 2; ++ks)
            bv_[nt][ks] = __builtin_bit_cast(half8,
                *(const u32x4*)(wotu + col*64 + kseg*8 + ks*32));
    }
    f32x4 cacc[4][2];
    #pragma unroll
    for (int mt = 0; mt < 4; ++mt)
        #pragma unroll
        for (int nt = 0; nt < 2; ++nt)
            cacc[mt][nt] = (f32x4){0.f, 0.f, 0.f, 0.f};
    #pragma unroll
    for (int ks = 0; ks < 2; ++ks)
        #pragma unroll
        for (int mt = 0; mt < 4; ++mt)
            #pragma unroll
            for (int nt = 0; nt < 2; ++nt)
                cacc[mt][nt] = __builtin_amdgcn_mfma_f32_16x16x32_f16(
                    av[mt][ks], bv_[nt][ks], cacc[mt][nt], 0, 0, 0);

    // C-write f32 into own 8KB slice (only own wave reads)
    #pragma unroll
    for (int mt = 0; mt < 4; ++mt)
        #pragma unroll
        for (int nt = 0; nt < 2; ++nt)
            #pragma unroll
            for (int r = 0; r < 4; ++r) {
                const int row = wv*64 + mt*16 + kseg*4 + r;
                const int col = nt*16 + frow;
                *(float*)(smem + row*128
                    + (((unsigned)(col*4)) ^ ((((unsigned)(row >> 2)) & 7u) << 4)))
                    = cacc[mt][nt][r];
            }
    asm volatile("s_waitcnt lgkmcnt(0)" ::: "memory");

    // C-read own row (= tid), add bo, LN, pixel-shuffle store
    float cv[32];
    {
        const unsigned sw = (((unsigned)(tid >> 2)) & 7u) << 4;
        #pragma unroll
        for (int j = 0; j < 8; ++j) {
            const f32x4 c4 = *(const f32x4*)(smem + tid*128 + (((unsigned)(j*16)) ^ sw));
            cv[j*4+0] = c4[0]; cv[j*4+1] = c4[1]; cv[j*4+2] = c4[2]; cv[j*4+3] = c4[3];
        }
    }
    float mu = 0.f;
    #pragma unroll
    for (int oc = 0; oc < 32; ++oc) { cv[oc] += bo[oc]; mu += cv[oc]; }
    mu *= (1.f/32.f);
    float var = 0.f;
    #pragma unroll
    for (int oc = 0; oc < 32; ++oc) { float d = cv[oc] - mu; var += d*d; }
    var *= (1.f/32.f);
    const float rstd = rsqrtf(var + 1e-5f);

    const int q   = tid & 3;
    const int pix = tid >> 2;
    const int gy = ty*8 + (pix >> 3), gx = tx*8 + (pix & 7);
    const int Y = gy*2 + (q >> 1), X = gx*2 + (q & 1);
    float* op = out + (((size_t)b*32)*256 + Y)*256 + X;
    #pragma unroll
    for (int oc = 0; oc < 32; ++oc) {
        float v = (cv[oc] - mu) * rstd * ln_g[oc] + ln_b[oc];
        op[(size_t)oc * 65536] = v;
    }
}

// ---------------------------------------------------------------------------
extern "C" void kernel_launch(void* const* d_in, const int* in_sizes, int n_in,
                              void* d_out, int out_size, void* d_ws, size_t ws_size,
                              hipStream_t stream)
{
    const float* x        = (const float*)d_in[0];
    const float* up_query = (const float*)d_in[1];
    const float* Wk  = (const float*)d_in[2];
    const float* bk  = (const float*)d_in[3];
    const float* Wv  = (const float*)d_in[4];
    const float* bv  = (const float*)d_in[5];
    const float* Wq  = (const float*)d_in[6];
    const float* bq  = (const float*)d_in[7];
    const float* Wka = (const float*)d_in[8];
    const float* bka = (const float*)d_in[9];
    const float* Wva = (const float*)d_in[10];
    const float* bva = (const float*)d_in[11];
    const float* Wo  = (const float*)d_in[12];
    const float* bo  = (const float*)d_in[13];
    const float* rel_pos = (const float*)d_in[14];
    const float* ln_g = (const float*)d_in[15];
    const float* ln_b = (const float*)d_in[16];

    float* ws  = (float*)d_ws;
    float* out = (float*)d_out;

    if (ws_size < (size_t)WS_DWORDS * 4) return;

    k0_fuse<<<8, 256, 0, stream>>>(up_query, Wk, bk, Wv, bv, Wq, bq,
                                   Wka, bka, Wva, bva, Wo, rel_pos, ws);
    k2_attn<<<2048, 256, 0, stream>>>(x, ws, bo, ln_g, ln_b, out);
}